// Round 1
// baseline (721.314 us; speedup 1.0000x reference)
//
#include <hip/hip_runtime.h>
#include <hip/hip_fp16.h>

typedef _Float16 f16;
typedef _Float16 half8 __attribute__((ext_vector_type(8)));
typedef float f32x4 __attribute__((ext_vector_type(4)));

#define NBAT 4
#define NT   2048
#define NC   2048
#define NHEAD 16
#define HD   128
#define NM   8192            // NBAT*NT rows
#define N3C  6144
#define QK_LD 4096           // row stride of the Q|K buffer (elems)
#define ATT_SCALE 0.088388347648318447f   // 1/sqrt(128)

static __device__ __forceinline__ void gload16(const void* g, void* l) {
  __builtin_amdgcn_global_load_lds(
      (const __attribute__((address_space(1))) unsigned int*)g,
      (__attribute__((address_space(3))) unsigned int*)l, 16, 0, 0);
}

// ---------------- converts ----------------

__global__ __launch_bounds__(256) void cvt_x_f16(const float* __restrict__ in,
                                                 f16* __restrict__ out) {
  size_t i = ((size_t)blockIdx.x * 256 + threadIdx.x) * 8;
  float4 a = *(const float4*)(in + i);
  float4 b = *(const float4*)(in + i + 4);
  half8 o;
  o[0] = (f16)a.x; o[1] = (f16)a.y; o[2] = (f16)a.z; o[3] = (f16)a.w;
  o[4] = (f16)b.x; o[5] = (f16)b.y; o[6] = (f16)b.z; o[7] = (f16)b.w;
  *(half8*)(out + i) = o;
}

// in: [R][CC] f32  ->  out: [CC][R] f16
__global__ __launch_bounds__(256) void cvt_tr_f16(const float* __restrict__ in,
                                                  f16* __restrict__ out,
                                                  int R, int CC) {
  __shared__ float tile[32][33];
  int cb = blockIdx.x * 32, rb = blockIdx.y * 32;
  int lx = threadIdx.x & 31, ly = threadIdx.x >> 5;  // ly 0..7
  for (int i = 0; i < 32; i += 8)
    tile[ly + i][lx] = in[(size_t)(rb + ly + i) * CC + cb + lx];
  __syncthreads();
  for (int i = 0; i < 32; i += 8)
    out[(size_t)(cb + ly + i) * R + rb + lx] = (f16)tile[lx][ly + i];
}

// ---------------- GEMM: C[M,N] = A[M,K] * BT[N,K]^T + bias ----------------
// OUTMODE 0: f32 out [M][N].  OUTMODE 1: QKV split -> f16 qk[M][4096] (cols<4096)
//                                       + f16 vT[(b*16+h)*128+d][2048] (cols>=4096)
template <int OUTMODE>
__global__ __launch_bounds__(256, 2)
void gemm_bt(const f16* __restrict__ A, const f16* __restrict__ BT,
             const float* __restrict__ bias,
             f16* __restrict__ oqk, f16* __restrict__ ovT,
             float* __restrict__ of32, int M, int N, int K) {
  __shared__ f16 As[128 * 32];
  __shared__ f16 Bs[128 * 32];
  const int tid = threadIdx.x;
  const int w = tid >> 6, lane = tid & 63;
  const int lr = lane & 15, lg = lane >> 4;
  const int wm = w >> 1, wn = w & 1;
  const int bm = blockIdx.y, bn = blockIdx.x;

  const int srow = lane >> 2;        // row within 16-row staging chunk
  const int skoff = (lane & 3) * 8;  // k offset (elems) within 32

  // per-instruction staging source row pointers (k added in loop)
  const f16* asrc[2];
  const f16* bsrc[2];
  for (int t = 0; t < 2; ++t) {
    int idx = w * 2 + t;
    asrc[t] = A + (size_t)(bm * 128 + idx * 16 + srow) * K + skoff;
    bsrc[t] = BT + (size_t)(bn * 128 + idx * 16 + srow) * K + skoff;
  }

  f32x4 acc[4][4] = {};

  for (int kt = 0; kt < K; kt += 32) {
    for (int t = 0; t < 2; ++t) {
      int idx = w * 2 + t;
      gload16(asrc[t] + kt, (void*)(As + idx * 512));
      gload16(bsrc[t] + kt, (void*)(Bs + idx * 512));
    }
    __syncthreads();
    half8 af[4], bf[4];
    for (int mi = 0; mi < 4; ++mi)
      af[mi] = *(const half8*)(As + (wm * 64 + mi * 16 + lr) * 32 + lg * 8);
    for (int ni = 0; ni < 4; ++ni)
      bf[ni] = *(const half8*)(Bs + (wn * 64 + ni * 16 + lr) * 32 + lg * 8);
    for (int mi = 0; mi < 4; ++mi)
      for (int ni = 0; ni < 4; ++ni)
        acc[mi][ni] = __builtin_amdgcn_mfma_f32_16x16x32_f16(
            af[mi], bf[ni], acc[mi][ni], 0, 0, 0);
    __syncthreads();
  }

  for (int ni = 0; ni < 4; ++ni) {
    int col = bn * 128 + wn * 64 + ni * 16 + lr;
    float bv = bias[col];
    for (int mi = 0; mi < 4; ++mi) {
      int row0 = bm * 128 + wm * 64 + mi * 16 + lg * 4;
      f32x4 v = acc[mi][ni];
      for (int r = 0; r < 4; ++r) {
        float val = v[r] + bv;
        int row = row0 + r;
        if (OUTMODE == 0) {
          of32[(size_t)row * N + col] = val;
        } else {
          if (col < 4096) {
            oqk[(size_t)row * QK_LD + col] = (f16)val;
          } else {
            int dfull = col - 4096;
            int hh = dfull >> 7, dd = dfull & 127;
            int bb = row >> 11, tt = row & 2047;
            ovT[((size_t)(bb * NHEAD + hh) * HD + dd) * NT + tt] = (f16)val;
          }
        }
      }
    }
  }
}

// ---------------- flash attention ----------------
// qk: [8192][4096] f16 (Q cols 0..2047, K cols 2048..4095)
// vT: [b*16+h][128][2048] f16
// y : [8192][2048] f16  (row = b*T+t, col = h*128+d)
__global__ __launch_bounds__(256, 2)
void attn_fwd(const f16* __restrict__ qk, const f16* __restrict__ vT,
              f16* __restrict__ y) {
  const int qt = blockIdx.x & 31;
  const int bh = blockIdx.x >> 5;  // b*16+h
  const int b = bh >> 4, h = bh & 15;
  const int tid = threadIdx.x, w = tid >> 6, lane = tid & 63;
  const int lr = lane & 15, lg = lane >> 4;

  __shared__ f16 Ks[64 * 128];   // XOR-swizzled rows (16B chunk ^ (row&7))
  __shared__ f16 Vs[128 * 64];   // V^T rows, XOR-swizzled (8B chunk ^ (d&7))
  __shared__ f16 Ps[4][16 * 64]; // per-wave P tile, XOR-swizzled

  // Q fragments (A-operand), row = lr within wave's 16-row stripe
  half8 qf[4];
  {
    const f16* qp = qk + (size_t)(b * NT + qt * 64 + w * 16 + lr) * QK_LD +
                    h * HD + lg * 8;
    for (int dc = 0; dc < 4; ++dc) qf[dc] = *(const half8*)(qp + dc * 32);
  }

  f32x4 accy[8] = {};
  float mrow[4] = {-1e30f, -1e30f, -1e30f, -1e30f};
  float lrow[4] = {0.f, 0.f, 0.f, 0.f};

  // staging source bases (per-lane, pre-swizzled global addresses)
  const char* kbase[4];
  const char* vbase[4];
  for (int j = 0; j < 4; ++j) {
    int idx = w * 4 + j;
    {
      int row = idx * 4 + lg;                     // kv row in tile
      int swz = (lr * 16) ^ ((row & 7) << 4);     // byte offset in 256B row
      kbase[j] = (const char*)qk +
                 ((size_t)(b * NT + row) * QK_LD + 2048 + h * HD) * 2 + swz;
    }
    {
      int d = idx * 8 + (lane >> 3);
      int cj = (lane & 7) ^ (d & 7);              // 16B source chunk in 128B row
      vbase[j] = (const char*)vT + ((size_t)(bh * HD + d) * NT + cj * 8) * 2;
    }
  }

  for (int kt = 0; kt < 32; ++kt) {
    __syncthreads();  // previous tile fully consumed
    for (int j = 0; j < 4; ++j) {
      int idx = w * 4 + j;
      gload16(kbase[j] + (size_t)kt * (64 * QK_LD * 2), (void*)((char*)Ks + idx * 1024));
      gload16(vbase[j] + (size_t)kt * 128, (void*)((char*)Vs + idx * 1024));
    }
    __syncthreads();

    // S = Q K^T : 16 rows x 64 cols per wave
    f32x4 sa[4] = {};
    for (int nb = 0; nb < 4; ++nb) {
      int kvr = nb * 16 + lr;
      const char* kr = (const char*)Ks + kvr * 256;
      int s7 = (kvr & 7) << 4;
      for (int dc = 0; dc < 4; ++dc) {
        half8 kb = *(const half8*)(kr + ((dc * 64 + lg * 16) ^ s7));
        sa[nb] = __builtin_amdgcn_mfma_f32_16x16x32_f16(qf[dc], kb, sa[nb], 0, 0, 0);
      }
    }

    // online softmax (rows i = lg*4+r, replicated across the 16-lane group)
    float sv[4][4], pm[4];
    for (int r = 0; r < 4; ++r) pm[r] = -1e30f;
    for (int nb = 0; nb < 4; ++nb)
      for (int r = 0; r < 4; ++r) {
        float s = sa[nb][r] * ATT_SCALE;
        sv[nb][r] = s;
        pm[r] = fmaxf(pm[r], s);
      }
    for (int r = 0; r < 4; ++r)
      for (int off = 1; off < 16; off <<= 1)
        pm[r] = fmaxf(pm[r], __shfl_xor(pm[r], off));
    float alpha[4], rsum[4];
    for (int r = 0; r < 4; ++r) {
      float mnew = fmaxf(mrow[r], pm[r]);
      alpha[r] = __expf(mrow[r] - mnew);
      mrow[r] = mnew;
      rsum[r] = 0.f;
    }
    for (int nb = 0; nb < 4; ++nb)
      for (int r = 0; r < 4; ++r) {
        float p = __expf(sv[nb][r] - mrow[r]);
        rsum[r] += p;
        int prow = lg * 4 + r;
        int chunk = (nb * 2 + (lr >> 3)) ^ (prow & 7);
        Ps[w][prow * 64 + chunk * 8 + (lr & 7)] = (f16)p;
      }
    for (int r = 0; r < 4; ++r) {
      for (int off = 1; off < 16; off <<= 1) rsum[r] += __shfl_xor(rsum[r], off);
      lrow[r] = lrow[r] * alpha[r] + rsum[r];
    }
    for (int db = 0; db < 8; ++db)
      for (int r = 0; r < 4; ++r) accy[db][r] *= alpha[r];

    // PV: Y[i,d] += P[i,kv] * V[kv,d]
    half8 pa[2];
    for (int kc = 0; kc < 2; ++kc) {
      int chunk = (kc * 4 + lg) ^ (lr & 7);
      pa[kc] = *(const half8*)(&Ps[w][lr * 64 + chunk * 8]);
    }
    for (int db = 0; db < 8; ++db) {
      int d = db * 16 + lr;
      const char* vr = (const char*)Vs + d * 128;
      int d7 = d & 7;
      for (int kc = 0; kc < 2; ++kc) {
        half8 vb = *(const half8*)(vr + (((kc * 4 + lg) ^ d7) * 16));
        accy[db] = __builtin_amdgcn_mfma_f32_16x16x32_f16(pa[kc], vb, accy[db], 0, 0, 0);
      }
    }
  }

  float inv[4];
  for (int r = 0; r < 4; ++r) inv[r] = 1.f / lrow[r];
  f16* yp = y + (size_t)(b * NT + qt * 64 + w * 16 + lg * 4) * NC + h * HD + lr;
  for (int db = 0; db < 8; ++db)
    for (int r = 0; r < 4; ++r)
      yp[(size_t)r * NC + db * 16] = (f16)(accy[db][r] * inv[r]);
}

// ---------------- launcher ----------------
extern "C" void kernel_launch(void* const* d_in, const int* in_sizes, int n_in,
                              void* d_out, int out_size, void* d_ws, size_t ws_size,
                              hipStream_t stream) {
  (void)in_sizes; (void)n_in; (void)out_size; (void)ws_size;
  const float* x      = (const float*)d_in[0];
  const float* w_attn = (const float*)d_in[1];
  const float* b_attn = (const float*)d_in[2];
  const float* w_proj = (const float*)d_in[3];
  const float* b_proj = (const float*)d_in[4];
  float* out = (float*)d_out;

  char* p = (char*)d_ws;
  f16* xh  = (f16*)p; p += (size_t)NM * NC * 2;          // 33.5 MB
  f16* waT = (f16*)p; p += (size_t)N3C * NC * 2;         // 25.2 MB
  f16* wpT = (f16*)p; p += (size_t)NC * NC * 2;          //  8.4 MB
  f16* qkb = (f16*)p; p += (size_t)NM * QK_LD * 2;       // 67.1 MB
  f16* vT  = (f16*)p; p += (size_t)NBAT * NHEAD * HD * NT * 2; // 33.5 MB
  f16* yh  = (f16*)p; p += (size_t)NM * NC * 2;          // 33.5 MB

  cvt_x_f16<<<8192, 256, 0, stream>>>(x, xh);
  cvt_tr_f16<<<dim3(192, 64), 256, 0, stream>>>(w_attn, waT, NC, N3C);
  cvt_tr_f16<<<dim3(64, 64), 256, 0, stream>>>(w_proj, wpT, NC, NC);
  gemm_bt<1><<<dim3(48, 64), 256, 0, stream>>>(xh, waT, b_attn, qkb, vT, nullptr,
                                               NM, N3C, NC);
  attn_fwd<<<2048, 256, 0, stream>>>(qkb, vT, yh);
  gemm_bt<0><<<dim3(16, 64), 256, 0, stream>>>(yh, wpT, b_proj, nullptr, nullptr,
                                               out, NM, NC, NC);
}

// Round 2
// 565.410 us; speedup vs baseline: 1.2757x; 1.2757x over previous
//
#include <hip/hip_runtime.h>
#include <hip/hip_fp16.h>

typedef _Float16 f16;
typedef _Float16 half8 __attribute__((ext_vector_type(8)));
typedef float f32x4 __attribute__((ext_vector_type(4)));

#define NBAT 4
#define NT   2048
#define NC   2048
#define NHEAD 16
#define HD   128
#define NM   8192            // NBAT*NT rows
#define N3C  6144
#define QK_LD 4096           // row stride of the Q|K buffer (elems)
#define ATT_SCALE 0.088388347648318447f   // 1/sqrt(128)

static __device__ __forceinline__ void gload16(const void* g, void* l) {
  __builtin_amdgcn_global_load_lds(
      (const __attribute__((address_space(1))) unsigned int*)g,
      (__attribute__((address_space(3))) unsigned int*)l, 16, 0, 0);
}

// ---------------- converts ----------------

__global__ __launch_bounds__(256) void cvt_x_f16(const float* __restrict__ in,
                                                 f16* __restrict__ out) {
  size_t i = ((size_t)blockIdx.x * 256 + threadIdx.x) * 8;
  float4 a = *(const float4*)(in + i);
  float4 b = *(const float4*)(in + i + 4);
  half8 o;
  o[0] = (f16)a.x; o[1] = (f16)a.y; o[2] = (f16)a.z; o[3] = (f16)a.w;
  o[4] = (f16)b.x; o[5] = (f16)b.y; o[6] = (f16)b.z; o[7] = (f16)b.w;
  *(half8*)(out + i) = o;
}

// in: [R][CC] f32  ->  out: [CC][R] f16
__global__ __launch_bounds__(256) void cvt_tr_f16(const float* __restrict__ in,
                                                  f16* __restrict__ out,
                                                  int R, int CC) {
  __shared__ float tile[32][33];
  int cb = blockIdx.x * 32, rb = blockIdx.y * 32;
  int lx = threadIdx.x & 31, ly = threadIdx.x >> 5;  // ly 0..7
  for (int i = 0; i < 32; i += 8)
    tile[ly + i][lx] = in[(size_t)(rb + ly + i) * CC + cb + lx];
  __syncthreads();
  for (int i = 0; i < 32; i += 8)
    out[(size_t)(cb + ly + i) * R + rb + lx] = (f16)tile[lx][ly + i];
}

// ---------------- GEMM: C[M,N] = A[M,K] * BT[N,K]^T + bias ----------------
template <int OUTMODE>
__global__ __launch_bounds__(256, 2)
void gemm_bt(const f16* __restrict__ A, const f16* __restrict__ BT,
             const float* __restrict__ bias,
             f16* __restrict__ oqk, f16* __restrict__ ovT,
             float* __restrict__ of32, int M, int N, int K) {
  __shared__ f16 As[128 * 32];
  __shared__ f16 Bs[128 * 32];
  const int tid = threadIdx.x;
  const int w = tid >> 6, lane = tid & 63;
  const int lr = lane & 15, lg = lane >> 4;
  const int wm = w >> 1, wn = w & 1;
  const int bm = blockIdx.y, bn = blockIdx.x;

  const int srow = lane >> 2;        // row within 16-row staging chunk
  const int skoff = (lane & 3) * 8;  // k offset (elems) within 32

  const f16* asrc[2];
  const f16* bsrc[2];
  for (int t = 0; t < 2; ++t) {
    int idx = w * 2 + t;
    asrc[t] = A + (size_t)(bm * 128 + idx * 16 + srow) * K + skoff;
    bsrc[t] = BT + (size_t)(bn * 128 + idx * 16 + srow) * K + skoff;
  }

  f32x4 acc[4][4] = {};

  for (int kt = 0; kt < K; kt += 32) {
    for (int t = 0; t < 2; ++t) {
      int idx = w * 2 + t;
      gload16(asrc[t] + kt, (void*)(As + idx * 512));
      gload16(bsrc[t] + kt, (void*)(Bs + idx * 512));
    }
    __syncthreads();
    half8 af[4], bf[4];
    for (int mi = 0; mi < 4; ++mi)
      af[mi] = *(const half8*)(As + (wm * 64 + mi * 16 + lr) * 32 + lg * 8);
    for (int ni = 0; ni < 4; ++ni)
      bf[ni] = *(const half8*)(Bs + (wn * 64 + ni * 16 + lr) * 32 + lg * 8);
    for (int mi = 0; mi < 4; ++mi)
      for (int ni = 0; ni < 4; ++ni)
        acc[mi][ni] = __builtin_amdgcn_mfma_f32_16x16x32_f16(
            af[mi], bf[ni], acc[mi][ni], 0, 0, 0);
    __syncthreads();
  }

  for (int ni = 0; ni < 4; ++ni) {
    int col = bn * 128 + wn * 64 + ni * 16 + lr;
    float bv = bias[col];
    for (int mi = 0; mi < 4; ++mi) {
      int row0 = bm * 128 + wm * 64 + mi * 16 + lg * 4;
      f32x4 v = acc[mi][ni];
      for (int r = 0; r < 4; ++r) {
        float val = v[r] + bv;
        int row = row0 + r;
        if (OUTMODE == 0) {
          of32[(size_t)row * N + col] = val;
        } else {
          if (col < 4096) {
            oqk[(size_t)row * QK_LD + col] = (f16)val;
          } else {
            int dfull = col - 4096;
            int hh = dfull >> 7, dd = dfull & 127;
            int bb = row >> 11, tt = row & 2047;
            ovT[((size_t)(bb * NHEAD + hh) * HD + dd) * NT + tt] = (f16)val;
          }
        }
      }
    }
  }
}

// ---------------- flash attention (v2: dbuf 2-phase, QBLK=128) ----------------
// qk: [8192][4096] f16 (Q cols 0..2047, K cols 2048..4095)
// vT: [b*16+h][128][2048] f16
// y : [8192][2048] f16  (row = b*T+t, col = h*128+d)
__global__ __launch_bounds__(256, 2)
void attn_fwd(const f16* __restrict__ qk, const f16* __restrict__ vT,
              f16* __restrict__ y) {
  const int bid = blockIdx.x;
  const int sid = (bid & 7) * 128 + (bid >> 3);  // bijective XCD swizzle (1024 % 8 == 0)
  const int qt = sid & 15;       // 16 q-tiles of 128 rows
  const int bh = sid >> 4;       // b*16+h
  const int b = bh >> 4, h = bh & 15;
  const int tid = threadIdx.x, w = tid >> 6, lane = tid & 63;
  const int lr = lane & 15, lg = lane >> 4;

  __shared__ f16 Ks[2][64 * 128];    // 2 x 16 KB, XOR-swizzled rows
  __shared__ f16 Vs[2][128 * 64];    // 2 x 16 KB, V^T rows, XOR-swizzled
  __shared__ f16 Ps[4][2][16 * 64];  // per wave, per stripe P tile (16 KB)

  // Q fragments: stripes s=0,1 -> rows qt*128 + w*32 + s*16 + lr
  half8 qf[2][4];
  for (int s = 0; s < 2; ++s) {
    const f16* qp = qk + (size_t)(b * NT + qt * 128 + w * 32 + s * 16 + lr) * QK_LD +
                    h * HD + lg * 8;
    for (int dc = 0; dc < 4; ++dc) qf[s][dc] = *(const half8*)(qp + dc * 32);
  }

  f32x4 accy[2][8] = {};
  f32x4 lacc[2] = {};
  float mrow[2][4];
  for (int s = 0; s < 2; ++s)
    for (int r = 0; r < 4; ++r) mrow[s][r] = -1e30f;

  half8 onev;
  for (int j = 0; j < 8; ++j) onev[j] = (f16)1.0f;

  // staging source bases (per-lane, pre-swizzled global addresses)
  const char* kbase[4];
  const char* vbase[4];
  for (int j = 0; j < 4; ++j) {
    int idx = w * 4 + j;
    {
      int row = idx * 4 + lg;                  // kv row in tile
      int swz = (lr * 16) ^ ((row & 7) << 4);  // byte offset in 256B row
      kbase[j] = (const char*)qk +
                 ((size_t)(b * NT + row) * QK_LD + 2048 + h * HD) * 2 + swz;
    }
    {
      int d = idx * 8 + (lane >> 3);
      int cj = (lane & 7) ^ (d & 7);           // 16B source chunk in 128B row
      vbase[j] = (const char*)vT + ((size_t)(bh * HD + d) * NT + cj * 8) * 2;
    }
  }

  // prologue: stage tile 0 -> buf 0
  for (int j = 0; j < 4; ++j) {
    int idx = w * 4 + j;
    gload16(kbase[j], (void*)((char*)Ks[0] + idx * 1024));
    gload16(vbase[j], (void*)((char*)Vs[0] + idx * 1024));
  }
  __syncthreads();

  int cur = 0;
  for (int kt = 0; kt < 32; ++kt) {
    // issue next tile's staging first; its vmcnt drains at the end barrier
    if (kt + 1 < 32) {
      for (int j = 0; j < 4; ++j) {
        int idx = w * 4 + j;
        gload16(kbase[j] + (size_t)(kt + 1) * (64 * QK_LD * 2),
                (void*)((char*)Ks[cur ^ 1] + idx * 1024));
        gload16(vbase[j] + (size_t)(kt + 1) * 128,
                (void*)((char*)Vs[cur ^ 1] + idx * 1024));
      }
    }

    // S = Q K^T : both stripes share each K fragment
    f32x4 sa[2][4] = {};
    for (int nb = 0; nb < 4; ++nb) {
      int kvr = nb * 16 + lr;
      const char* kr = (const char*)Ks[cur] + kvr * 256;
      int s7 = (kvr & 7) << 4;
      for (int dc = 0; dc < 4; ++dc) {
        half8 kb = *(const half8*)(kr + ((dc * 64 + lg * 16) ^ s7));
        sa[0][nb] = __builtin_amdgcn_mfma_f32_16x16x32_f16(qf[0][dc], kb, sa[0][nb], 0, 0, 0);
        sa[1][nb] = __builtin_amdgcn_mfma_f32_16x16x32_f16(qf[1][dc], kb, sa[1][nb], 0, 0, 0);
      }
    }

    // online softmax per stripe (defer-max: skip reduce+rescale unless needed)
    for (int s = 0; s < 2; ++s) {
      float sv[4][4];
      float pml[4] = {-1e30f, -1e30f, -1e30f, -1e30f};
      for (int nb = 0; nb < 4; ++nb)
        for (int r = 0; r < 4; ++r) {
          float x = sa[s][nb][r] * ATT_SCALE;
          sv[nb][r] = x;
          pml[r] = fmaxf(pml[r], x);
        }
      bool ok = true;
      for (int r = 0; r < 4; ++r) ok &= (pml[r] <= mrow[s][r] + 8.0f);
      if (!__all(ok)) {
        for (int r = 0; r < 4; ++r) {
          for (int off = 1; off < 16; off <<= 1)
            pml[r] = fmaxf(pml[r], __shfl_xor(pml[r], off));
          float mn = fmaxf(mrow[s][r], pml[r]);
          float al = __expf(mrow[s][r] - mn);
          mrow[s][r] = mn;
          lacc[s][r] *= al;
          for (int db = 0; db < 8; ++db) accy[s][db][r] *= al;
        }
      }
      for (int nb = 0; nb < 4; ++nb)
        for (int r = 0; r < 4; ++r) {
          float p = __expf(sv[nb][r] - mrow[s][r]);
          int prow = lg * 4 + r;
          int chunk = (nb * 2 + (lr >> 3)) ^ (prow & 7);
          Ps[w][s][prow * 64 + chunk * 8 + (lr & 7)] = (f16)p;
        }
    }

    // P fragments for both stripes
    half8 pa[2][2];
    for (int s = 0; s < 2; ++s)
      for (int kc = 0; kc < 2; ++kc) {
        int chunk = (kc * 4 + lg) ^ (lr & 7);
        pa[s][kc] = *(const half8*)(&Ps[w][s][lr * 64 + chunk * 8]);
      }
    // row-sum via MFMA against all-ones B (replaces shuffle-reduce)
    for (int s = 0; s < 2; ++s)
      for (int kc = 0; kc < 2; ++kc)
        lacc[s] = __builtin_amdgcn_mfma_f32_16x16x32_f16(pa[s][kc], onev, lacc[s], 0, 0, 0);

    // PV: both stripes share each V fragment
    for (int db = 0; db < 8; ++db) {
      int d = db * 16 + lr;
      const char* vr = (const char*)Vs[cur] + d * 128;
      int d7 = d & 7;
      for (int kc = 0; kc < 2; ++kc) {
        half8 vb = *(const half8*)(vr + (((kc * 4 + lg) ^ d7) * 16));
        accy[0][db] = __builtin_amdgcn_mfma_f32_16x16x32_f16(pa[0][kc], vb, accy[0][db], 0, 0, 0);
        accy[1][db] = __builtin_amdgcn_mfma_f32_16x16x32_f16(pa[1][kc], vb, accy[1][db], 0, 0, 0);
      }
    }

    __syncthreads();  // drains this tile's staging vmcnt; frees buf cur for next stage
    cur ^= 1;
  }

  for (int s = 0; s < 2; ++s) {
    f32x4 inv;
    for (int r = 0; r < 4; ++r) inv[r] = 1.0f / lacc[s][r];
    f16* yp = y + (size_t)(b * NT + qt * 128 + w * 32 + s * 16 + lg * 4) * NC +
              h * HD + lr;
    for (int db = 0; db < 8; ++db)
      for (int r = 0; r < 4; ++r)
        yp[(size_t)r * NC + db * 16] = (f16)(accy[s][db][r] * inv[r]);
  }
}

// ---------------- launcher ----------------
extern "C" void kernel_launch(void* const* d_in, const int* in_sizes, int n_in,
                              void* d_out, int out_size, void* d_ws, size_t ws_size,
                              hipStream_t stream) {
  (void)in_sizes; (void)n_in; (void)out_size; (void)ws_size;
  const float* x      = (const float*)d_in[0];
  const float* w_attn = (const float*)d_in[1];
  const float* b_attn = (const float*)d_in[2];
  const float* w_proj = (const float*)d_in[3];
  const float* b_proj = (const float*)d_in[4];
  float* out = (float*)d_out;

  char* p = (char*)d_ws;
  f16* xh  = (f16*)p; p += (size_t)NM * NC * 2;          // 33.5 MB
  f16* waT = (f16*)p; p += (size_t)N3C * NC * 2;         // 25.2 MB
  f16* wpT = (f16*)p; p += (size_t)NC * NC * 2;          //  8.4 MB
  f16* qkb = (f16*)p; p += (size_t)NM * QK_LD * 2;       // 67.1 MB
  f16* vT  = (f16*)p; p += (size_t)NBAT * NHEAD * HD * NT * 2; // 33.5 MB
  f16* yh  = (f16*)p; p += (size_t)NM * NC * 2;          // 33.5 MB

  cvt_x_f16<<<8192, 256, 0, stream>>>(x, xh);
  cvt_tr_f16<<<dim3(192, 64), 256, 0, stream>>>(w_attn, waT, NC, N3C);
  cvt_tr_f16<<<dim3(64, 64), 256, 0, stream>>>(w_proj, wpT, NC, NC);
  gemm_bt<1><<<dim3(48, 64), 256, 0, stream>>>(xh, waT, b_attn, qkb, vT, nullptr,
                                               NM, N3C, NC);
  attn_fwd<<<1024, 256, 0, stream>>>(qkb, vT, yh);
  gemm_bt<0><<<dim3(16, 64), 256, 0, stream>>>(yh, wpT, b_proj, nullptr, nullptr,
                                               out, NM, NC, NC);
}

// Round 3
// 496.871 us; speedup vs baseline: 1.4517x; 1.1379x over previous
//
#include <hip/hip_runtime.h>
#include <hip/hip_fp16.h>

typedef _Float16 f16;
typedef _Float16 half8 __attribute__((ext_vector_type(8)));
typedef float f32x4 __attribute__((ext_vector_type(4)));

#define NBAT 4
#define NT   2048
#define NC   2048
#define NHEAD 16
#define HD   128
#define NM   8192            // NBAT*NT rows
#define N3C  6144
#define QK_LD 4096           // row stride of the Q|K buffer (elems)
#define ATT_SCALE 0.088388347648318447f   // 1/sqrt(128)

static __device__ __forceinline__ void gload16(const void* g, void* l) {
  __builtin_amdgcn_global_load_lds(
      (const __attribute__((address_space(1))) unsigned int*)g,
      (__attribute__((address_space(3))) unsigned int*)l, 16, 0, 0);
}

// ---------------- converts ----------------

__global__ __launch_bounds__(256) void cvt_x_f16(const float* __restrict__ in,
                                                 f16* __restrict__ out) {
  size_t i = ((size_t)blockIdx.x * 256 + threadIdx.x) * 8;
  float4 a = *(const float4*)(in + i);
  float4 b = *(const float4*)(in + i + 4);
  half8 o;
  o[0] = (f16)a.x; o[1] = (f16)a.y; o[2] = (f16)a.z; o[3] = (f16)a.w;
  o[4] = (f16)b.x; o[5] = (f16)b.y; o[6] = (f16)b.z; o[7] = (f16)b.w;
  *(half8*)(out + i) = o;
}

// in: [R][CC] f32  ->  out: [CC][R] f16
__global__ __launch_bounds__(256) void cvt_tr_f16(const float* __restrict__ in,
                                                  f16* __restrict__ out,
                                                  int R, int CC) {
  __shared__ float tile[32][33];
  int cb = blockIdx.x * 32, rb = blockIdx.y * 32;
  int lx = threadIdx.x & 31, ly = threadIdx.x >> 5;  // ly 0..7
  for (int i = 0; i < 32; i += 8)
    tile[ly + i][lx] = in[(size_t)(rb + ly + i) * CC + cb + lx];
  __syncthreads();
  for (int i = 0; i < 32; i += 8)
    out[(size_t)(cb + ly + i) * R + rb + lx] = (f16)tile[lx][ly + i];
}

// ---- GEMM 256x256 tile, BK=64, 8 waves, dbuf LDS + counted vmcnt ----
// C[M,N] = A[M,K] * BT[N,K]^T + bias
// OUTMODE 0: f32 out [M][N].  OUTMODE 1: QKV split -> f16 qk[M][4096] (cols<4096)
//                                       + f16 vT[(b*16+h)*128+d][2048] (cols>=4096)
template <int OUTMODE>
__global__ __launch_bounds__(512, 2)
void gemm256(const f16* __restrict__ A, const f16* __restrict__ BT,
             const float* __restrict__ bias,
             f16* __restrict__ oqk, f16* __restrict__ ovT,
             float* __restrict__ of32, int N, int K, int nbn) {
  __shared__ f16 sA[2][256 * 64];   // 2 x 32 KB, rows of 64 f16 (128 B)
  __shared__ f16 sB[2][256 * 64];   // chunk c of row r holds global chunk c^(r&7)

  const int tid = threadIdx.x;
  const int wv = tid >> 6, lane = tid & 63;
  const int lr = lane & 15, lg = lane >> 4;
  const int wm = wv >> 2, wn = wv & 3;   // 2 x 4 wave grid

  // bijective XCD swizzle (gridDim.x % 8 == 0 guaranteed by host)
  const int q8 = gridDim.x >> 3;
  const int sid = ((int)blockIdx.x & 7) * q8 + ((int)blockIdx.x >> 3);
  const int bm = sid / nbn, bn = sid % nbn;

  // staging: per thread 4 A-chunks + 4 B-chunks of 16 B per K-tile.
  // global chunk id g = j*512 + tid ; row = g>>3, lds chunk = g&7,
  // source k-chunk = (g&7) ^ (row&7)  (pre-swizzled source, linear LDS dest)
  const int srow = lane >> 3;              // row&7 within this thread's row
  const int schk = (lane & 7) ^ srow;      // swizzled source k-chunk
  const f16* aS = A + (size_t)(bm * 256 + wv * 8 + srow) * K + schk * 8;
  const f16* bS = BT + (size_t)(bn * 256 + wv * 8 + srow) * K + schk * 8;
  const size_t jstep = (size_t)64 * K;     // 64 rows of source

  const int NKT = K >> 6;
  f32x4 acc[8][4] = {};

  // prologue: stage K-tile 0 -> buf 0
#pragma unroll
  for (int j = 0; j < 4; ++j) {
    gload16(aS + j * jstep, (void*)(sA[0] + (j * 512 + wv * 64) * 8));
    gload16(bS + j * jstep, (void*)(sB[0] + (j * 512 + wv * 64) * 8));
  }

  for (int kt = 0; kt < NKT; ++kt) {
    const int c = kt & 1;
    if (kt + 1 < NKT) {
      const f16* aN = aS + (size_t)(kt + 1) * 64;
      const f16* bN = bS + (size_t)(kt + 1) * 64;
#pragma unroll
      for (int j = 0; j < 4; ++j) {
        gload16(aN + j * jstep, (void*)(sA[c ^ 1] + (j * 512 + wv * 64) * 8));
        gload16(bN + j * jstep, (void*)(sB[c ^ 1] + (j * 512 + wv * 64) * 8));
      }
      // wait for current tile's 8 loads only; next tile's 8 stay in flight
      asm volatile("s_waitcnt vmcnt(8)" ::: "memory");
    } else {
      asm volatile("s_waitcnt vmcnt(0)" ::: "memory");
    }
    __builtin_amdgcn_s_barrier();
    asm volatile("" ::: "memory");   // no LDS read hoists above the barrier

    const f16* pa = sA[c] + (wm * 128 + lr) * 64;
    const f16* pb = sB[c] + (wn * 64 + lr) * 64;
#pragma unroll
    for (int ks = 0; ks < 2; ++ks) {
      const int xc = ((ks * 4 + lg) ^ (lr & 7)) * 8;   // de-swizzle on read
      half8 a[8], b[4];
#pragma unroll
      for (int mf = 0; mf < 8; ++mf)
        a[mf] = *(const half8*)(pa + mf * (16 * 64) + xc);
#pragma unroll
      for (int nf = 0; nf < 4; ++nf)
        b[nf] = *(const half8*)(pb + nf * (16 * 64) + xc);
#pragma unroll
      for (int mf = 0; mf < 8; ++mf)
#pragma unroll
        for (int nf = 0; nf < 4; ++nf)
          acc[mf][nf] = __builtin_amdgcn_mfma_f32_16x16x32_f16(
              a[mf], b[nf], acc[mf][nf], 0, 0, 0);
    }
    asm volatile("" ::: "memory");   // no LDS read sinks below the barrier
    __builtin_amdgcn_s_barrier();    // frees buf c for overwrite next iter
  }

  // epilogue
#pragma unroll
  for (int nf = 0; nf < 4; ++nf) {
    const int col = bn * 256 + wn * 64 + nf * 16 + lr;
    const float bv = bias[col];
#pragma unroll
    for (int mf = 0; mf < 8; ++mf) {
      const int row0 = bm * 256 + wm * 128 + mf * 16 + lg * 4;
      f32x4 v = acc[mf][nf];
      if (OUTMODE == 0) {
#pragma unroll
        for (int r = 0; r < 4; ++r)
          of32[(size_t)(row0 + r) * N + col] = v[r] + bv;
      } else {
        if (col < 4096) {
#pragma unroll
          for (int r = 0; r < 4; ++r)
            oqk[(size_t)(row0 + r) * QK_LD + col] = (f16)(v[r] + bv);
        } else {
          const int dfull = col - 4096;
          const int hh = dfull >> 7, dd = dfull & 127;
#pragma unroll
          for (int r = 0; r < 4; ++r) {
            const int row = row0 + r;
            const int bb = row >> 11, tt = row & 2047;
            ovT[((size_t)(bb * NHEAD + hh) * HD + dd) * NT + tt] = (f16)(v[r] + bv);
          }
        }
      }
    }
  }
}

// ---------------- flash attention (dbuf 2-phase, QBLK=128) ----------------
// qk: [8192][4096] f16 (Q cols 0..2047, K cols 2048..4095)
// vT: [b*16+h][128][2048] f16
// y : [8192][2048] f16  (row = b*T+t, col = h*128+d)
__global__ __launch_bounds__(256, 2)
void attn_fwd(const f16* __restrict__ qk, const f16* __restrict__ vT,
              f16* __restrict__ y) {
  const int bid = blockIdx.x;
  const int sid = (bid & 7) * 128 + (bid >> 3);  // bijective XCD swizzle (1024 % 8 == 0)
  const int qt = sid & 15;       // 16 q-tiles of 128 rows
  const int bh = sid >> 4;       // b*16+h
  const int b = bh >> 4, h = bh & 15;
  const int tid = threadIdx.x, w = tid >> 6, lane = tid & 63;
  const int lr = lane & 15, lg = lane >> 4;

  __shared__ f16 Ks[2][64 * 128];    // 2 x 16 KB, XOR-swizzled rows
  __shared__ f16 Vs[2][128 * 64];    // 2 x 16 KB, V^T rows, XOR-swizzled
  __shared__ f16 Ps[4][2][16 * 64];  // per wave, per stripe P tile (16 KB)

  // Q fragments: stripes s=0,1 -> rows qt*128 + w*32 + s*16 + lr
  half8 qf[2][4];
  for (int s = 0; s < 2; ++s) {
    const f16* qp = qk + (size_t)(b * NT + qt * 128 + w * 32 + s * 16 + lr) * QK_LD +
                    h * HD + lg * 8;
    for (int dc = 0; dc < 4; ++dc) qf[s][dc] = *(const half8*)(qp + dc * 32);
  }

  f32x4 accy[2][8] = {};
  f32x4 lacc[2] = {};
  float mrow[2][4];
  for (int s = 0; s < 2; ++s)
    for (int r = 0; r < 4; ++r) mrow[s][r] = -1e30f;

  half8 onev;
  for (int j = 0; j < 8; ++j) onev[j] = (f16)1.0f;

  // staging source bases (per-lane, pre-swizzled global addresses)
  const char* kbase[4];
  const char* vbase[4];
  for (int j = 0; j < 4; ++j) {
    int idx = w * 4 + j;
    {
      int row = idx * 4 + lg;                  // kv row in tile
      int swz = (lr * 16) ^ ((row & 7) << 4);  // byte offset in 256B row
      kbase[j] = (const char*)qk +
                 ((size_t)(b * NT + row) * QK_LD + 2048 + h * HD) * 2 + swz;
    }
    {
      int d = idx * 8 + (lane >> 3);
      int cj = (lane & 7) ^ (d & 7);           // 16B source chunk in 128B row
      vbase[j] = (const char*)vT + ((size_t)(bh * HD + d) * NT + cj * 8) * 2;
    }
  }

  // prologue: stage tile 0 -> buf 0
  for (int j = 0; j < 4; ++j) {
    int idx = w * 4 + j;
    gload16(kbase[j], (void*)((char*)Ks[0] + idx * 1024));
    gload16(vbase[j], (void*)((char*)Vs[0] + idx * 1024));
  }
  __syncthreads();

  int cur = 0;
  for (int kt = 0; kt < 32; ++kt) {
    // issue next tile's staging first; its vmcnt drains at the end barrier
    if (kt + 1 < 32) {
      for (int j = 0; j < 4; ++j) {
        int idx = w * 4 + j;
        gload16(kbase[j] + (size_t)(kt + 1) * (64 * QK_LD * 2),
                (void*)((char*)Ks[cur ^ 1] + idx * 1024));
        gload16(vbase[j] + (size_t)(kt + 1) * 128,
                (void*)((char*)Vs[cur ^ 1] + idx * 1024));
      }
    }

    // S = Q K^T : both stripes share each K fragment
    f32x4 sa[2][4] = {};
    for (int nb = 0; nb < 4; ++nb) {
      int kvr = nb * 16 + lr;
      const char* kr = (const char*)Ks[cur] + kvr * 256;
      int s7 = (kvr & 7) << 4;
      for (int dc = 0; dc < 4; ++dc) {
        half8 kb = *(const half8*)(kr + ((dc * 64 + lg * 16) ^ s7));
        sa[0][nb] = __builtin_amdgcn_mfma_f32_16x16x32_f16(qf[0][dc], kb, sa[0][nb], 0, 0, 0);
        sa[1][nb] = __builtin_amdgcn_mfma_f32_16x16x32_f16(qf[1][dc], kb, sa[1][nb], 0, 0, 0);
      }
    }

    // online softmax per stripe (defer-max: skip reduce+rescale unless needed)
    for (int s = 0; s < 2; ++s) {
      float sv[4][4];
      float pml[4] = {-1e30f, -1e30f, -1e30f, -1e30f};
      for (int nb = 0; nb < 4; ++nb)
        for (int r = 0; r < 4; ++r) {
          float x = sa[s][nb][r] * ATT_SCALE;
          sv[nb][r] = x;
          pml[r] = fmaxf(pml[r], x);
        }
      bool ok = true;
      for (int r = 0; r < 4; ++r) ok &= (pml[r] <= mrow[s][r] + 8.0f);
      if (!__all(ok)) {
        for (int r = 0; r < 4; ++r) {
          for (int off = 1; off < 16; off <<= 1)
            pml[r] = fmaxf(pml[r], __shfl_xor(pml[r], off));
          float mn = fmaxf(mrow[s][r], pml[r]);
          float al = __expf(mrow[s][r] - mn);
          mrow[s][r] = mn;
          lacc[s][r] *= al;
          for (int db = 0; db < 8; ++db) accy[s][db][r] *= al;
        }
      }
      for (int nb = 0; nb < 4; ++nb)
        for (int r = 0; r < 4; ++r) {
          float p = __expf(sv[nb][r] - mrow[s][r]);
          int prow = lg * 4 + r;
          int chunk = (nb * 2 + (lr >> 3)) ^ (prow & 7);
          Ps[w][s][prow * 64 + chunk * 8 + (lr & 7)] = (f16)p;
        }
    }

    // P fragments for both stripes
    half8 pa[2][2];
    for (int s = 0; s < 2; ++s)
      for (int kc = 0; kc < 2; ++kc) {
        int chunk = (kc * 4 + lg) ^ (lr & 7);
        pa[s][kc] = *(const half8*)(&Ps[w][s][lr * 64 + chunk * 8]);
      }
    // row-sum via MFMA against all-ones B (replaces shuffle-reduce)
    for (int s = 0; s < 2; ++s)
      for (int kc = 0; kc < 2; ++kc)
        lacc[s] = __builtin_amdgcn_mfma_f32_16x16x32_f16(pa[s][kc], onev, lacc[s], 0, 0, 0);

    // PV: both stripes share each V fragment
    for (int db = 0; db < 8; ++db) {
      int d = db * 16 + lr;
      const char* vr = (const char*)Vs[cur] + d * 128;
      int d7 = d & 7;
      for (int kc = 0; kc < 2; ++kc) {
        half8 vb = *(const half8*)(vr + (((kc * 4 + lg) ^ d7) * 16));
        accy[0][db] = __builtin_amdgcn_mfma_f32_16x16x32_f16(pa[0][kc], vb, accy[0][db], 0, 0, 0);
        accy[1][db] = __builtin_amdgcn_mfma_f32_16x16x32_f16(pa[1][kc], vb, accy[1][db], 0, 0, 0);
      }
    }

    __syncthreads();  // drains this tile's staging vmcnt; frees buf cur for next stage
    cur ^= 1;
  }

  for (int s = 0; s < 2; ++s) {
    f32x4 inv;
    for (int r = 0; r < 4; ++r) inv[r] = 1.0f / lacc[s][r];
    f16* yp = y + (size_t)(b * NT + qt * 128 + w * 32 + s * 16 + lg * 4) * NC +
              h * HD + lr;
    for (int db = 0; db < 8; ++db)
      for (int r = 0; r < 4; ++r)
        yp[(size_t)r * NC + db * 16] = (f16)(accy[s][db][r] * inv[r]);
  }
}

// ---------------- launcher ----------------
extern "C" void kernel_launch(void* const* d_in, const int* in_sizes, int n_in,
                              void* d_out, int out_size, void* d_ws, size_t ws_size,
                              hipStream_t stream) {
  (void)in_sizes; (void)n_in; (void)out_size; (void)ws_size;
  const float* x      = (const float*)d_in[0];
  const float* w_attn = (const float*)d_in[1];
  const float* b_attn = (const float*)d_in[2];
  const float* w_proj = (const float*)d_in[3];
  const float* b_proj = (const float*)d_in[4];
  float* out = (float*)d_out;

  char* p = (char*)d_ws;
  f16* xh  = (f16*)p; p += (size_t)NM * NC * 2;          // 33.5 MB
  f16* waT = (f16*)p; p += (size_t)N3C * NC * 2;         // 25.2 MB
  f16* wpT = (f16*)p; p += (size_t)NC * NC * 2;          //  8.4 MB
  f16* qkb = (f16*)p; p += (size_t)NM * QK_LD * 2;       // 67.1 MB
  f16* vT  = (f16*)p; p += (size_t)NBAT * NHEAD * HD * NT * 2; // 33.5 MB
  f16* yh  = (f16*)p; p += (size_t)NM * NC * 2;          // 33.5 MB

  cvt_x_f16<<<8192, 256, 0, stream>>>(x, xh);
  cvt_tr_f16<<<dim3(192, 64), 256, 0, stream>>>(w_attn, waT, NC, N3C);
  cvt_tr_f16<<<dim3(64, 64), 256, 0, stream>>>(w_proj, wpT, NC, NC);
  // QKV: M=8192 -> 32 bm, N=6144 -> 24 bn, 768 blocks (div by 8)
  gemm256<1><<<768, 512, 0, stream>>>(xh, waT, b_attn, qkb, vT, nullptr,
                                      N3C, NC, 24);
  attn_fwd<<<1024, 256, 0, stream>>>(qkb, vT, yh);
  // proj: M=8192 -> 32 bm, N=2048 -> 8 bn, 256 blocks (div by 8)
  gemm256<0><<<256, 512, 0, stream>>>(yh, wpT, b_proj, nullptr, nullptr,
                                      out, NC, NC, 8);
}